// Round 3
// baseline (3977.589 us; speedup 1.0000x reference)
//
#include <hip/hip_runtime.h>
#include <hip/hip_bf16.h>
#include <stdint.h>

typedef __bf16 bf16_t;
typedef __bf16 bf16x8 __attribute__((ext_vector_type(8)));
typedef __bf16 bf16x4_t __attribute__((ext_vector_type(4)));
typedef float f32x4 __attribute__((ext_vector_type(4)));

#define T_STEPS 512
#define B_SZ 64
#define I_SZ 512
#define H_SZ 512
#define G4 2048         // 4*H
#define NB 4            // batch groups
#define BS 16           // batch rows per group
#define NC 32           // column groups per batch group
#define CS 16           // h cols per WG
#define KT 32           // K tiles of 32 (K = 1024)

// ws layout (bytes)
#define XBF_OFF   0ull
#define WBF_OFF   33554432ull                    // 512*64*512*2
#define BALL_OFF  (WBF_OFF + 4194304ull)         // 2048*1024*2
#define HEX_OFF   (BALL_OFF + 8192ull)           // 2048*4
#define FLG_OFF   (HEX_OFF + 131072ull)          // 2*64*512*2

__device__ __forceinline__ float sigmoid_fast(float x) {
  return 1.f / (1.f + __expf(-x));
}
__device__ __forceinline__ float tanh_fast(float x) {
  float xc = fminf(fmaxf(x, -10.f), 10.f);
  float e = __expf(2.f * xc);
  return (e - 1.f) / (e + 1.f);
}

// ---- device-coherent (L1+L2 bypass -> Infinity Cache) accessors ----
__device__ __forceinline__ uint4 load_b128_cc(const void* addr) {
  uint4 v;
  asm volatile("global_load_dwordx4 %0, %1, off sc0 sc1"
               : "=v"(v) : "v"(addr) : "memory");
  return v;
}
__device__ __forceinline__ uint32_t load_b32_cc(const void* addr) {
  uint32_t v;
  asm volatile("global_load_dword %0, %1, off sc0 sc1"
               : "=v"(v) : "v"(addr) : "memory");
  return v;
}
__device__ __forceinline__ void store_b16_cc(void* addr, uint32_t v) {
  asm volatile("global_store_short %0, %1, off sc0 sc1"
               :: "v"(addr), "v"(v) : "memory");
}
__device__ __forceinline__ void wait_vm0() {
  asm volatile("s_waitcnt vmcnt(0)" ::: "memory");
}

// ---------- prep: cast x to bf16 ----------
__global__ void prep_x(const float* __restrict__ x, bf16_t* __restrict__ xbf) {
  const int n4 = (T_STEPS * B_SZ * I_SZ) / 4;
  int i = blockIdx.x * blockDim.x + threadIdx.x;
  int stride = gridDim.x * blockDim.x;
  for (; i < n4; i += stride) {
    float4 v = ((const float4*)x)[i];
    bf16x4_t o = { (bf16_t)v.x, (bf16_t)v.y, (bf16_t)v.z, (bf16_t)v.w };
    ((bf16x4_t*)xbf)[i] = o;
  }
}

// ---------- prep: W_all bf16, b_all f32, zero h-exchange + flags ----------
__global__ void prep_rest(const float* __restrict__ wf, const float* __restrict__ wi,
                          const float* __restrict__ wg, const float* __restrict__ wo,
                          const float* __restrict__ bfv, const float* __restrict__ biv,
                          const float* __restrict__ bgv, const float* __restrict__ bov,
                          bf16_t* __restrict__ wbf, float* __restrict__ ball,
                          uint32_t* __restrict__ hexz, uint32_t* __restrict__ flg) {
  int gtid = blockIdx.x * blockDim.x + threadIdx.x;
  int stride = gridDim.x * blockDim.x;
  const int WCH = (G4 * 1024) / 4;  // 524288 float4 chunks
  for (int i = gtid; i < WCH; i += stride) {
    int r = i >> 8;               // W_all row (0..2047)
    int c = (i & 255) << 2;       // col base
    int g = r >> 9, sr = r & 511;
    const float* src = (g == 0) ? wf : (g == 1) ? wi : (g == 2) ? wg : wo;
    float4 v = *(const float4*)(src + (size_t)sr * 1024 + c);
    bf16x4_t o = { (bf16_t)v.x, (bf16_t)v.y, (bf16_t)v.z, (bf16_t)v.w };
    *(bf16x4_t*)(wbf + (size_t)r * 1024 + c) = o;
  }
  for (int i = gtid; i < G4; i += stride) {
    int g = i >> 9;
    const float* src = (g == 0) ? bfv : (g == 1) ? biv : (g == 2) ? bgv : bov;
    ball[i] = src[i & 511];
  }
  for (int i = gtid; i < (2 * B_SZ * H_SZ * 2) / 4; i += stride) hexz[i] = 0;
  for (int i = gtid; i < NB * NC * 4 * 2 / 4; i += stride) flg[i] = 0;  // 512B
}

// ---------- main recurrent kernel: 128 WGs, flag-based group sync ----------
__global__ __launch_bounds__(256, 1) void qlstm_main(
    const bf16_t* __restrict__ xbf, const bf16_t* __restrict__ wbf,
    const float* __restrict__ ball, bf16_t* __restrict__ hexch,
    uint16_t* __restrict__ flags, float* __restrict__ out) {
  const int wg = blockIdx.x;
  const int bg = wg >> 5;      // batch group 0..3
  const int ic = wg & 31;      // column group 0..31
  const int tid = threadIdx.x;
  const int wave = tid >> 6;   // 0..3 == gate index (N-tile)
  const int lane = tid & 63;
  const int l15 = lane & 15;
  const int quad = lane >> 4;

  // gate pre-activations, [parity][gate][col][row(+pad 20)]
  __shared__ float Gs[2][4][CS][20];

  // Register-resident B fragments: W_all row = gate*512 + ic*16 + (lane&15),
  // k = kt*32 + quad*8 .. +8  (B[k][n] = W_all[n][k])
  bf16x8 wfr[KT];
  {
    const bf16_t* wp = wbf + ((size_t)(wave * 512 + ic * CS + l15)) * 1024 + quad * 8;
#pragma unroll
    for (int kt = 0; kt < KT; ++kt)
      wfr[kt] = *(const bf16x8*)(wp + kt * 32);
  }

  // elementwise mapping: thread -> (batch row, h col) of this WG's 16x16 slice
  const int erow = tid >> 4;
  const int ecol = tid & 15;
  const float bias_f = ball[0 * 512 + ic * CS + ecol];
  const float bias_i = ball[1 * 512 + ic * CS + ecol];
  const float bias_g = ball[2 * 512 + ic * CS + ecol];
  const float bias_o = ball[3 * 512 + ic * CS + ecol];

  float c_state = 0.f;
  float h = 0.f;
  const size_t out_hx = (size_t)T_STEPS * B_SZ * H_SZ;
  const int brow = bg * BS + erow;
  const int hcol = ic * CS + ecol;
  uint16_t* myflag = flags + bg * 128 + ic * 4 + wave;
  const uint32_t* fp = (const uint32_t*)(flags + bg * 128);  // 64 dwords

#pragma unroll 1
  for (int t = 0; t < T_STEPS; ++t) {
    const int par = t & 1;

    // A-fragment direct loads (x half): row = l15, k = kt*32 + quad*8
    const bf16_t* xrow = xbf + ((size_t)t * B_SZ + bg * BS + l15) * I_SZ + quad * 8;
    bf16x8 xf[16];
#pragma unroll
    for (int kt = 0; kt < 16; ++kt)
      xf[kt] = *(const bf16x8*)(xrow + kt * 32);

    // wait for all 128 producer flags of this batch group to reach t
    if (t > 0) {
      const uint32_t need = (uint32_t)t;
      for (;;) {
        uint32_t v = load_b32_cc(fp + lane);
        if (__all(((v & 0xFFFFu) >= need) & ((v >> 16) >= need))) break;
        __builtin_amdgcn_s_sleep(1);
      }
    }

    // h half via coherent bypass loads
    uint4 hf[16];
    if (t > 0) {
      const bf16_t* hrow =
          hexch + (size_t)((par ^ 1) * B_SZ + bg * BS + l15) * H_SZ + quad * 8;
#pragma unroll
      for (int kt = 0; kt < 16; ++kt)
        hf[kt] = load_b128_cc(hrow + kt * 32);
    }

    // GEMM: one gate (16x16 C tile) per wave, 4 independent acc chains
    f32x4 a0 = {0, 0, 0, 0}, a1 = {0, 0, 0, 0}, a2 = {0, 0, 0, 0}, a3 = {0, 0, 0, 0};
#pragma unroll
    for (int kt = 0; kt < 16; kt += 4) {
      a0 = __builtin_amdgcn_mfma_f32_16x16x32_bf16(xf[kt + 0], wfr[kt + 0], a0, 0, 0, 0);
      a1 = __builtin_amdgcn_mfma_f32_16x16x32_bf16(xf[kt + 1], wfr[kt + 1], a1, 0, 0, 0);
      a2 = __builtin_amdgcn_mfma_f32_16x16x32_bf16(xf[kt + 2], wfr[kt + 2], a2, 0, 0, 0);
      a3 = __builtin_amdgcn_mfma_f32_16x16x32_bf16(xf[kt + 3], wfr[kt + 3], a3, 0, 0, 0);
    }
    if (t > 0) {
#pragma unroll
      for (int kt = 0; kt < 16; kt += 4) {
        bf16x8 h0 = *(bf16x8*)&hf[kt + 0];
        bf16x8 h1 = *(bf16x8*)&hf[kt + 1];
        bf16x8 h2 = *(bf16x8*)&hf[kt + 2];
        bf16x8 h3 = *(bf16x8*)&hf[kt + 3];
        a0 = __builtin_amdgcn_mfma_f32_16x16x32_bf16(h0, wfr[16 + kt + 0], a0, 0, 0, 0);
        a1 = __builtin_amdgcn_mfma_f32_16x16x32_bf16(h1, wfr[16 + kt + 1], a1, 0, 0, 0);
        a2 = __builtin_amdgcn_mfma_f32_16x16x32_bf16(h2, wfr[16 + kt + 2], a2, 0, 0, 0);
        a3 = __builtin_amdgcn_mfma_f32_16x16x32_bf16(h3, wfr[16 + kt + 3], a3, 0, 0, 0);
      }
    }
    f32x4 acc = (a0 + a1) + (a2 + a3);
    // C/D layout: col = lane&15, row = quad*4 + i  -> Gs[g][col][row]
    *(f32x4*)&Gs[par][wave][l15][quad * 4] = acc;
    __syncthreads();

    // LSTM cell (fp32), per-thread c state
    float fg = sigmoid_fast(Gs[par][0][ecol][erow] + bias_f);
    float ig = sigmoid_fast(Gs[par][1][ecol][erow] + bias_i);
    float gg = tanh_fast(Gs[par][2][ecol][erow] + bias_g);
    float og = sigmoid_fast(Gs[par][3][ecol][erow] + bias_o);
    c_state = fg * c_state + ig * gg;
    h = og * tanh_fast(c_state);

    // out store (drains together with h store), then publish h + flag per wave
    out[((size_t)t * B_SZ + brow) * H_SZ + hcol] = h;
    union { bf16_t b; unsigned short u; } cvt;
    cvt.b = (bf16_t)h;
    store_b16_cc(&hexch[(size_t)(par * B_SZ + brow) * H_SZ + hcol], (uint32_t)cvt.u);
    wait_vm0();  // this wave's h (and out) stores are at the coherence point
    if (lane == 0) store_b16_cc(myflag, (uint32_t)(t + 1));
  }

  out[out_hx + (size_t)brow * H_SZ + hcol] = h;
  out[out_hx + (size_t)(B_SZ * H_SZ) + (size_t)brow * H_SZ + hcol] = c_state;
}

extern "C" void kernel_launch(void* const* d_in, const int* in_sizes, int n_in,
                              void* d_out, int out_size, void* d_ws, size_t ws_size,
                              hipStream_t stream) {
  const float* x   = (const float*)d_in[0];
  const float* Wf  = (const float*)d_in[1];
  const float* bfv = (const float*)d_in[2];
  const float* Wi  = (const float*)d_in[3];
  const float* biv = (const float*)d_in[4];
  const float* Wg  = (const float*)d_in[5];
  const float* bgv = (const float*)d_in[6];
  const float* Wo  = (const float*)d_in[7];
  const float* bov = (const float*)d_in[8];
  float* out = (float*)d_out;

  char* ws = (char*)d_ws;
  bf16_t* xbf   = (bf16_t*)(ws + XBF_OFF);
  bf16_t* wbf   = (bf16_t*)(ws + WBF_OFF);
  float*  ball  = (float*)(ws + BALL_OFF);
  bf16_t* hexch = (bf16_t*)(ws + HEX_OFF);
  uint16_t* flg = (uint16_t*)(ws + FLG_OFF);

  prep_x<<<dim3(2048), dim3(256), 0, stream>>>(x, xbf);
  prep_rest<<<dim3(1024), dim3(256), 0, stream>>>(Wf, Wi, Wg, Wo, bfv, biv, bgv, bov,
                                                  wbf, ball, (uint32_t*)hexch,
                                                  (uint32_t*)flg);
  qlstm_main<<<dim3(NB * NC), dim3(256), 0, stream>>>(xbf, wbf, ball, hexch, flg, out);
}

// Round 7
// 1909.780 us; speedup vs baseline: 2.0827x; 2.0827x over previous
//
#include <hip/hip_runtime.h>
#include <hip/hip_bf16.h>
#include <stdint.h>

typedef __bf16 bf16_t;
typedef __bf16 bf16x8 __attribute__((ext_vector_type(8)));
typedef __bf16 bf16x4_t __attribute__((ext_vector_type(4)));
typedef float f32x4 __attribute__((ext_vector_type(4)));

#define T_STEPS 512
#define B_SZ 64
#define I_SZ 512
#define H_SZ 512
#define G4 2048         // 4*H
#define NB 4            // batch groups
#define BS 16           // batch rows per group
#define NC 32           // column groups per batch group
#define CS 16           // h cols per WG
#define KT 32           // K tiles of 32 (K = 1024)
#define A_STRIDE 1032   // LDS row stride elems

// ws layout (bytes)
#define XBF_OFF   0ull
#define WBF_OFF   33554432ull                    // 512*64*512*2
#define BALL_OFF  (WBF_OFF + 4194304ull)         // 2048*1024*2
#define HEX_OFF   (BALL_OFF + 8192ull)           // 2048*4
#define FLG_OFF   (HEX_OFF + 131072ull)          // 2*64*512*2
// FLG region: NB * T_STEPS * NC uint32 = 256 KiB, write-once per (bg,t,ic)

__device__ __forceinline__ float sigmoid_fast(float x) {
  return 1.f / (1.f + __expf(-x));
}
__device__ __forceinline__ float tanh_fast(float x) {
  float xc = fminf(fmaxf(x, -10.f), 10.f);
  float e = __expf(2.f * xc);
  return (e - 1.f) / (e + 1.f);
}

// ---- device-coherent (L1+L2 bypass -> Infinity Cache) DATA accessors ----
// (R2-validated for the h payload; SIGNALING uses compiler atomics only.)
__device__ __forceinline__ uint4 load_b128_cc(const void* addr) {
  uint4 v;
  asm volatile("global_load_dwordx4 %0, %1, off sc0 sc1"
               : "=v"(v) : "v"(addr) : "memory");
  return v;
}
__device__ __forceinline__ void store_b16_cc(void* addr, uint32_t v) {
  asm volatile("global_store_short %0, %1, off sc0 sc1"
               :: "v"(addr), "v"(v) : "memory");
}
__device__ __forceinline__ void wait_vm0() {
  asm volatile("s_waitcnt vmcnt(0)" ::: "memory");
}

// ---------- prep: cast x to bf16 ----------
__global__ void prep_x(const float* __restrict__ x, bf16_t* __restrict__ xbf) {
  const int n4 = (T_STEPS * B_SZ * I_SZ) / 4;
  int i = blockIdx.x * blockDim.x + threadIdx.x;
  int stride = gridDim.x * blockDim.x;
  for (; i < n4; i += stride) {
    float4 v = ((const float4*)x)[i];
    bf16x4_t o = { (bf16_t)v.x, (bf16_t)v.y, (bf16_t)v.z, (bf16_t)v.w };
    ((bf16x4_t*)xbf)[i] = o;
  }
}

// ---------- prep: W_all bf16, b_all f32, zero h-exchange + flags ----------
__global__ void prep_rest(const float* __restrict__ wf, const float* __restrict__ wi,
                          const float* __restrict__ wg, const float* __restrict__ wo,
                          const float* __restrict__ bfv, const float* __restrict__ biv,
                          const float* __restrict__ bgv, const float* __restrict__ bov,
                          bf16_t* __restrict__ wbf, float* __restrict__ ball,
                          uint32_t* __restrict__ hexz, uint32_t* __restrict__ flg) {
  int gtid = blockIdx.x * blockDim.x + threadIdx.x;
  int stride = gridDim.x * blockDim.x;
  const int WCH = (G4 * 1024) / 4;  // 524288 float4 chunks
  for (int i = gtid; i < WCH; i += stride) {
    int r = i >> 8;               // W_all row (0..2047)
    int c = (i & 255) << 2;       // col base
    int g = r >> 9, sr = r & 511;
    const float* src = (g == 0) ? wf : (g == 1) ? wi : (g == 2) ? wg : wo;
    float4 v = *(const float4*)(src + (size_t)sr * 1024 + c);
    bf16x4_t o = { (bf16_t)v.x, (bf16_t)v.y, (bf16_t)v.z, (bf16_t)v.w };
    *(bf16x4_t*)(wbf + (size_t)r * 1024 + c) = o;
  }
  for (int i = gtid; i < G4; i += stride) {
    int g = i >> 9;
    const float* src = (g == 0) ? bfv : (g == 1) ? biv : (g == 2) ? bgv : bov;
    ball[i] = src[i & 511];
  }
  for (int i = gtid; i < (2 * B_SZ * H_SZ * 2) / 4; i += stride) hexz[i] = 0;
  for (int i = gtid; i < NB * T_STEPS * NC; i += stride) flg[i] = 0;  // 256 KiB
}

// ---------- main recurrent kernel: 128 WGs, write-once atomic flags ----------
__global__ __launch_bounds__(256, 1) void qlstm_main(
    const bf16_t* __restrict__ xbf, const bf16_t* __restrict__ wbf,
    const float* __restrict__ ball, bf16_t* __restrict__ hexch,
    uint32_t* __restrict__ flg, float* __restrict__ out) {
  const int wg = blockIdx.x;
  const int bg = wg >> 5;      // batch group 0..3
  const int ic = wg & 31;      // column group 0..31
  const int tid = threadIdx.x;
  const int wave = tid >> 6;   // 0..3 == gate index (N-tile)
  const int lane = tid & 63;
  const int l15 = lane & 15;
  const int quad = lane >> 4;

  __shared__ __align__(16) bf16_t As[BS * A_STRIDE];   // [16 rows][x(512)|h(512)]
  __shared__ float Gs[BS][4][CS + 2];                  // gate pre-acts [row][g][col]

  // Register-resident B fragments: W_all row = gate*512 + ic*16 + (lane&15),
  // k = kt*32 + quad*8  (B[k][n] = W_all[n][k])
  bf16x8 wfr[KT];
  {
    const bf16_t* wp = wbf + ((size_t)(wave * 512 + ic * CS + l15)) * 1024 + quad * 8;
#pragma unroll
    for (int kt = 0; kt < KT; ++kt)
      wfr[kt] = *(const bf16x8*)(wp + kt * 32);
  }

  // elementwise mapping: thread -> (batch row, h col) of this WG's 16x16 slice
  const int erow = tid >> 4;
  const int ecol = tid & 15;
  const float bias_f = ball[0 * 512 + ic * CS + ecol];
  const float bias_i = ball[1 * 512 + ic * CS + ecol];
  const float bias_g = ball[2 * 512 + ic * CS + ecol];
  const float bias_o = ball[3 * 512 + ic * CS + ecol];

  float c_state = 0.f;
  float h = 0.f;
  const size_t out_hx = (size_t)T_STEPS * B_SZ * H_SZ;
  const int brow = bg * BS + erow;
  const int hcol = ic * CS + ecol;

  // staging geometry (16B chunks): 1024 chunks over 256 threads, 4 each
  int srow[4], scol[4];
#pragma unroll
  for (int q = 0; q < 4; ++q) {
    int chunk = q * 256 + tid;          // 0..1023
    srow[q] = chunk >> 6;               // 0..15
    scol[q] = (chunk & 63) * 8;         // bf16 col base, step 8 (16B)
  }

#pragma unroll 1
  for (int t = 0; t < T_STEPS; ++t) {
    const int par = t & 1;

    // ---- x(t) loads issued early (normal cached); complete under the poll
    uint4 xr[4];
    {
      const bf16_t* xs = xbf + ((size_t)t * B_SZ + bg * BS) * I_SZ;
#pragma unroll
      for (int q = 0; q < 4; ++q)
        xr[q] = *(const uint4*)&xs[srow[q] * I_SZ + scol[q]];
    }

    // ---- wait: all 32 producers of this batch group signaled step t-1
    if (t > 0) {
      const uint32_t* stepflags =
          flg + ((size_t)bg * T_STEPS + (t - 1)) * NC;
      for (;;) {
        uint32_t v = __hip_atomic_load(&stepflags[lane & 31], __ATOMIC_RELAXED,
                                       __HIP_MEMORY_SCOPE_AGENT);
        if (__all((int)(v != 0))) break;
        __builtin_amdgcn_s_sleep(1);
      }
    }

    // ---- h(t-1) via coherent bypass loads (t=0: buffer 1 pre-zeroed)
    uint4 hr[4];
    {
      const bf16_t* hs = hexch + (size_t)((par ^ 1) * B_SZ + bg * BS) * H_SZ;
#pragma unroll
      for (int q = 0; q < 4; ++q)
        hr[q] = load_b128_cc(&hs[srow[q] * H_SZ + scol[q]]);
    }

    // ---- stage A = [x | h] into LDS
#pragma unroll
    for (int q = 0; q < 4; ++q)
      *(uint4*)&As[srow[q] * A_STRIDE + scol[q]] = xr[q];
    wait_vm0();  // drain bypass h loads
#pragma unroll
    for (int q = 0; q < 4; ++q)
      *(uint4*)&As[srow[q] * A_STRIDE + 512 + scol[q]] = hr[q];
    __syncthreads();  // S1: As ready

    // ---- GEMM: one gate (16x16 C tile) per wave, K=1024, 4 acc chains
    f32x4 a0 = {0, 0, 0, 0}, a1 = {0, 0, 0, 0}, a2 = {0, 0, 0, 0}, a3 = {0, 0, 0, 0};
    const bf16_t* ap = &As[l15 * A_STRIDE + quad * 8];
#pragma unroll
    for (int kt = 0; kt < KT; kt += 4) {
      bf16x8 f0 = *(const bf16x8*)(ap + (kt + 0) * 32);
      bf16x8 f1 = *(const bf16x8*)(ap + (kt + 1) * 32);
      bf16x8 f2 = *(const bf16x8*)(ap + (kt + 2) * 32);
      bf16x8 f3 = *(const bf16x8*)(ap + (kt + 3) * 32);
      a0 = __builtin_amdgcn_mfma_f32_16x16x32_bf16(f0, wfr[kt + 0], a0, 0, 0, 0);
      a1 = __builtin_amdgcn_mfma_f32_16x16x32_bf16(f1, wfr[kt + 1], a1, 0, 0, 0);
      a2 = __builtin_amdgcn_mfma_f32_16x16x32_bf16(f2, wfr[kt + 2], a2, 0, 0, 0);
      a3 = __builtin_amdgcn_mfma_f32_16x16x32_bf16(f3, wfr[kt + 3], a3, 0, 0, 0);
    }
    f32x4 acc = (a0 + a1) + (a2 + a3);
    // C/D layout: col = lane&15, row = quad*4 + i
#pragma unroll
    for (int i = 0; i < 4; ++i) Gs[quad * 4 + i][wave][l15] = acc[i];
    __syncthreads();  // S2: Gs ready

    // ---- LSTM cell (fp32), per-thread c state
    float fg = sigmoid_fast(Gs[erow][0][ecol] + bias_f);
    float ig = sigmoid_fast(Gs[erow][1][ecol] + bias_i);
    float gg = tanh_fast(Gs[erow][2][ecol] + bias_g);
    float og = sigmoid_fast(Gs[erow][3][ecol] + bias_o);
    c_state = fg * c_state + ig * gg;
    h = og * tanh_fast(c_state);

    // ---- publish h, drain, WG-wide barrier, atomic signal (R2-proven order)
    union { bf16_t b; unsigned short u; } cvt;
    cvt.b = (bf16_t)h;
    store_b16_cc(&hexch[(size_t)(par * B_SZ + brow) * H_SZ + hcol], (uint32_t)cvt.u);
    wait_vm0();          // this wave's h stores at the coherence point
    __syncthreads();     // S3: whole WG's h stores drained
    if (tid == 0)
      __hip_atomic_store(&flg[((size_t)bg * T_STEPS + t) * NC + ic], 1u,
                         __ATOMIC_RELAXED, __HIP_MEMORY_SCOPE_AGENT);

    // ---- out store (off critical path)
    out[((size_t)t * B_SZ + brow) * H_SZ + hcol] = h;
  }

  out[out_hx + (size_t)brow * H_SZ + hcol] = h;
  out[out_hx + (size_t)(B_SZ * H_SZ) + (size_t)brow * H_SZ + hcol] = c_state;
}

extern "C" void kernel_launch(void* const* d_in, const int* in_sizes, int n_in,
                              void* d_out, int out_size, void* d_ws, size_t ws_size,
                              hipStream_t stream) {
  const float* x   = (const float*)d_in[0];
  const float* Wf  = (const float*)d_in[1];
  const float* bfv = (const float*)d_in[2];
  const float* Wi  = (const float*)d_in[3];
  const float* biv = (const float*)d_in[4];
  const float* Wg  = (const float*)d_in[5];
  const float* bgv = (const float*)d_in[6];
  const float* Wo  = (const float*)d_in[7];
  const float* bov = (const float*)d_in[8];
  float* out = (float*)d_out;

  char* ws = (char*)d_ws;
  bf16_t* xbf   = (bf16_t*)(ws + XBF_OFF);
  bf16_t* wbf   = (bf16_t*)(ws + WBF_OFF);
  float*  ball  = (float*)(ws + BALL_OFF);
  bf16_t* hexch = (bf16_t*)(ws + HEX_OFF);
  uint32_t* flg = (uint32_t*)(ws + FLG_OFF);

  prep_x<<<dim3(2048), dim3(256), 0, stream>>>(x, xbf);
  prep_rest<<<dim3(1024), dim3(256), 0, stream>>>(Wf, Wi, Wg, Wo, bfv, biv, bgv, bov,
                                                  wbf, ball, (uint32_t*)hexch, flg);
  qlstm_main<<<dim3(NB * NC), dim3(256), 0, stream>>>(xbf, wbf, ball, hexch, flg, out);
}